// Round 21
// baseline (43.058 us; speedup 1.0000x reference)
//
#include <hip/hip_runtime.h>
#include <stdint.h>

// DSN few-shot classifier, MI355X.
// out[q][w] = log_softmax_w( s_w ),  s_w = z_w^T Ghat_w z_w,
// z_w = M_w^T q (raw support dots),  Ghat = G^{-1} - v v^T/(v^T G v).
//
// R20: R19's profile showed dsn_zs takes ~40us even with query L3-resident
// (no-fill replay: 39.9us @ 131GB/s) and VGPR=36 -> the compiler never
// hoisted the kt-loop loads; ~8 serial latency exposures at parked clock ARE
// the kernel. Fix: STRUCTURAL hoist -- all 16 query loads + all 40 P loads
// into named register arrays before any consumer (deps force back-to-back
// issue, ONE exposure), launch_bounds(256,2) for VGPR headroom.
// Solve/prep/post = R19 verbatim (timed-best 42.9us).
//
// ws layout:
//   [0,      4000)   G    : 5*100 double
//   [4096,   6096)   Ghat : 5*100 float
//   [8192,   172032) P    : 80*1024 bf16 (way w rows 16w..16w+9; rest zero)
//   [262144, 5505024) Z   : [80][16384] float (compact, split-summed)

typedef __attribute__((ext_vector_type(4))) float f32x4;
typedef __attribute__((ext_vector_type(8))) short s16x8;

#define WS_G_OFF    0
#define WS_GH_OFF   4096
#define WS_P_OFF    8192
#define WS_Z_OFF    262144

#define RDL(x, l) __uint_as_float(__builtin_amdgcn_readlane(__float_as_uint(x), (l)))

__device__ __forceinline__ unsigned short f2bf(float f) {
  unsigned int u = __float_as_uint(f);
  u += 0x7FFFu + ((u >> 16) & 1u);   // round-to-nearest-even
  return (unsigned short)(u >> 16);
}

// int64 vs int32 one-hot labels detection (validated R0).
__device__ __forceinline__ bool labels_int64(const int* L) {
  int cnt = 0; bool oddz = true;
  #pragma unroll
  for (int t = 0; t < 20; ++t) {
    int v = L[t];
    if (t & 1) { if (v) oddz = false; }
    else       { if (v) cnt++; }
  }
  return oddz && (cnt == 2);
}

__device__ __forceinline__ int cls_of(const int* L, bool is64, int i) {
  int best = -0x7fffffff, c = 0;
  #pragma unroll
  for (int j = 0; j < 5; ++j) {
    int v = is64 ? L[i * 10 + 2 * j] : L[i * 5 + j];
    if (v > best) { best = v; c = j; }
  }
  return c;
}

// ---- Kernel 1: gram (blocks 0..68) + pack P (blocks 69..148) --------------
__global__ __launch_bounds__(256) void dsn_prep(const float* __restrict__ support,
                                                const int* __restrict__ labels,
                                                double* __restrict__ G,
                                                unsigned short* __restrict__ P) {
  int b = blockIdx.x;
  bool is64 = labels_int64(labels);

  if (b < 69) {                        // ---- gram: one wave per (w,a,b) pair
    int wid  = b * 4 + (threadIdx.x >> 6);
    int lane = threadIdx.x & 63;
    if (wid >= 275) return;
    int w = wid / 55, p = wid % 55;
    int a = 0;
    while (p >= 10 - a) { p -= 10 - a; a++; }
    int bb = a + p;

    int myc = (lane < 50) ? cls_of(labels, is64, lane) : -1;
    unsigned long long mask = __ballot(lane < 50 && myc == w);

    unsigned long long m = mask;
    for (int i = 0; i < a; ++i) m &= m - 1;
    int ia = __ffsll((unsigned long long)m) - 1;
    m = mask;
    for (int i = 0; i < bb; ++i) m &= m - 1;
    int ib = __ffsll((unsigned long long)m) - 1;

    const float* A = support + ia * 1024;
    const float* B = support + ib * 1024;
    double acc = 0.0;
    #pragma unroll
    for (int i = 0; i < 16; ++i) {
      int d = lane + 64 * i;
      acc += (double)A[d] * (double)B[d];
    }
    #pragma unroll
    for (int off = 32; off > 0; off >>= 1) acc += __shfl_xor(acc, off);
    if (lane == 0) {
      G[(w * 10 + a) * 10 + bb] = acc;
      G[(w * 10 + bb) * 10 + a] = acc;
    }
  } else {                             // ---- pack: one block per P row
    int r = b - 69;                    // 0..79
    int w = r >> 4, kk = r & 15;
    int t = threadIdx.x;
    unsigned short* Prow = P + r * 1024;
    if (kk >= 10) {                    // zero-pad rows (block-uniform)
      #pragma unroll
      for (int j = 0; j < 4; ++j) Prow[t + 256 * j] = 0;
      return;
    }
    __shared__ int sid;
    if (t < 64) {
      int myc = (t < 50) ? cls_of(labels, is64, t) : -1;
      unsigned long long mask = __ballot(t < 50 && myc == w);
      if (t == 0) {
        unsigned long long m = mask;
        for (int z = 0; z < kk; ++z) m &= m - 1;
        sid = __ffsll(m) - 1;
      }
    }
    __syncthreads();
    const float* src = support + (size_t)sid * 1024;
    #pragma unroll
    for (int j = 0; j < 4; ++j) Prow[t + 256 * j] = f2bf(src[t + 256 * j]);
  }
}

// ---- Kernel 2: solve (blocks 0..4) + split-K-in-LDS GEMM (blocks 5..1028) --
__global__ __launch_bounds__(256, 2) void dsn_zs(const float* __restrict__ query,
                                                 const unsigned short* __restrict__ P,
                                                 const double* __restrict__ G,
                                                 float* __restrict__ Ghat,
                                                 float* __restrict__ Z) {
  if (blockIdx.x < 5) {
    // ====== solve (R19 proven): GJ inverse + shifted power iteration ======
    if (threadIdx.x >= 64) return;
    int w = blockIdx.x;
    int li = threadIdx.x;
    int rr = (li < 10) ? li : 0;
    const double* Gr = G + w * 100 + rr * 10;

    float o[10], g[10], h[10];
    #pragma unroll
    for (int j = 0; j < 10; ++j) {
      o[j] = (float)Gr[j];
      g[j] = o[j];
      h[j] = (li == j) ? 1.f : 0.f;
    }

    // Gauss-Jordan on [G | I] (SPD): h -> G^{-1} row li
    #pragma unroll
    for (int k = 0; k < 10; ++k) {
      float piv = 1.f / RDL(g[k], k);
      float pg[10], ph[10];
      #pragma unroll
      for (int j = 0; j < 10; ++j) {
        pg[j] = RDL(g[j], k) * piv;
        ph[j] = RDL(h[j], k) * piv;
      }
      float f = g[k];
      bool isk = (li == k);
      #pragma unroll
      for (int j = 0; j < 10; ++j) {
        g[j] = isk ? pg[j] : g[j] - f * pg[j];
        h[j] = isk ? ph[j] : h[j] - f * ph[j];
      }
    }

    // B = Ginv / diagmax
    float b[10];
    float d = h[0];
    #pragma unroll
    for (int k = 1; k < 10; ++k) d = (li == k) ? h[k] : d;
    float dm = RDL(d, 0);
    #pragma unroll
    for (int k = 1; k < 10; ++k) dm = fmaxf(dm, RDL(d, k));
    float rn = 1.f / dm;
    #pragma unroll
    for (int j = 0; j < 10; ++j) b[j] = h[j] * rn;
    float db = d * rn;

    // trace, argmax-diag, shift sigma = mean of non-dominant diag
    int jmx = 0;
    float bv = RDL(db, 0);
    float trB = bv;
    #pragma unroll
    for (int k = 1; k < 10; ++k) {
      float t2 = RDL(db, k);
      trB += t2;
      if (t2 > bv) { bv = t2; jmx = k; }   // uniform
    }
    float sigma = (trB - bv) * (1.f / 9.f);
    sigma = fminf(fmaxf(sigma, 0.f), 0.92f);
    float rs = 1.f / (bv - sigma);

    // 16 shifted-scaled power iterations from e_jmx
    float x = (li == jmx) ? 1.f : 0.f;
    #pragma unroll
    for (int it = 0; it < 16; ++it) {
      float xn = 0.f;
      #pragma unroll
      for (int k = 0; k < 10; ++k) xn += b[k] * RDL(x, k);
      x = rs * (xn - sigma * x);
    }
    // 2 plain-B matvecs + renorm
    #pragma unroll
    for (int it = 0; it < 2; ++it) {
      float xn = 0.f;
      #pragma unroll
      for (int k = 0; k < 10; ++k) xn += b[k] * RDL(x, k);
      float ax = fabsf(xn);
      float mx = RDL(ax, 0);
      #pragma unroll
      for (int k = 1; k < 10; ++k) mx = fmaxf(mx, RDL(ax, k));
      x = xn * (1.f / mx);
    }
    float v = x;

    // denom = v^T G v; Ghat = Ginv - v v^T / denom
    float gv = 0.f;
    #pragma unroll
    for (int k = 0; k < 10; ++k) gv += o[k] * RDL(v, k);
    float tn = v * gv;
    float denom = RDL(tn, 0);
    #pragma unroll
    for (int k = 1; k < 10; ++k) denom += RDL(tn, k);
    float rden = 1.f / denom;
    if (li < 10) {
      #pragma unroll
      for (int j = 0; j < 10; ++j)
        Ghat[w * 100 + li * 10 + j] = h[j] - v * RDL(v, j) * rden;
    }
    return;
  }

  // ====== GEMM: block = 16 queries; wave = one 256-elem K-split ===========
  __shared__ float Zsh[4][80][17];     // padded: conflict-free

  int t    = threadIdx.x;
  int wave = t >> 6;                   // K-split 0..3
  int lane = t & 63;
  int q0   = (blockIdx.x - 5) * 16;
  int qrow = lane & 15;
  int kbase = wave * 256 + (lane >> 4) * 8;

  const float* qp = query + (size_t)(q0 + qrow) * 1024 + kbase;
  const unsigned short* up = P + qrow * 1024 + kbase;

  // ---- phase 1: issue ALL loads (deps force back-to-back issue) ----
  f32x4 ql[8], qh[8];
  #pragma unroll
  for (int kt = 0; kt < 8; ++kt) {
    ql[kt] = *(const f32x4*)(qp + kt * 32);
    qh[kt] = *(const f32x4*)(qp + kt * 32 + 4);
  }
  s16x8 pv[8][5];
  #pragma unroll
  for (int kt = 0; kt < 8; ++kt)
    #pragma unroll
    for (int w = 0; w < 5; ++w)
      pv[kt][w] = *(const s16x8*)(up + w * 16384 + kt * 32);

  // ---- phase 2: convert query to bf16 (frees ql/qh as it goes) ----
  s16x8 bfv[8];
  #pragma unroll
  for (int kt = 0; kt < 8; ++kt) {
    s16x8 bf;
    bf[0] = (short)f2bf(ql[kt][0]); bf[1] = (short)f2bf(ql[kt][1]);
    bf[2] = (short)f2bf(ql[kt][2]); bf[3] = (short)f2bf(ql[kt][3]);
    bf[4] = (short)f2bf(qh[kt][0]); bf[5] = (short)f2bf(qh[kt][1]);
    bf[6] = (short)f2bf(qh[kt][2]); bf[7] = (short)f2bf(qh[kt][3]);
    bfv[kt] = bf;
  }

  // ---- phase 3: pure MFMA (no memory on the critical path) ----
  f32x4 acc[5];
  #pragma unroll
  for (int w = 0; w < 5; ++w) acc[w] = (f32x4){0.f, 0.f, 0.f, 0.f};
  #pragma unroll
  for (int kt = 0; kt < 8; ++kt) {
    #pragma unroll
    for (int w = 0; w < 5; ++w)
      acc[w] = __builtin_amdgcn_mfma_f32_16x16x32_bf16(pv[kt][w], bfv[kt],
                                                       acc[w], 0, 0, 0);
  }

  // park partial z: D[row=s][col=q]; row=(lane>>4)*4+reg, col=lane&15 (m89)
  int rowbase = (lane >> 4) * 4;
  #pragma unroll
  for (int w = 0; w < 5; ++w) {
    #pragma unroll
    for (int r = 0; r < 4; ++r)
      Zsh[wave][w * 16 + rowbase + r][qrow] = acc[w][r];
  }
  __syncthreads();

  // split-sum in LDS, write compact Z (1280 floats; deterministic order)
  #pragma unroll
  for (int idx = 0; idx < 5; ++idx) {
    int e = t + idx * 256;             // 0..1279
    int s = e >> 4, c = e & 15;
    float z = Zsh[0][s][c] + Zsh[1][s][c] + Zsh[2][s][c] + Zsh[3][s][c];
    Z[(size_t)s * 16384 + q0 + c] = z;
  }
}

// ---- Kernel 3: epilogue — quadratic forms + log_softmax (R13 proven) ------
__global__ __launch_bounds__(256) void dsn_post(const float* __restrict__ Ghat,
                                                const float* __restrict__ Z,
                                                float* __restrict__ out) {
  __shared__ float Gh[500];
  int t = threadIdx.x;
  for (int i = t; i < 500; i += 256) Gh[i] = Ghat[i];
  __syncthreads();
  int q = blockIdx.x * 256 + t;

  float zv[50];
  #pragma unroll
  for (int w = 0; w < 5; ++w)
    #pragma unroll
    for (int s = 0; s < 10; ++s)
      zv[w * 10 + s] = Z[(size_t)(w * 16 + s) * 16384 + q];   // coalesced

  float sv[5];
  #pragma unroll
  for (int w = 0; w < 5; ++w) {
    float s = 0.f;
    #pragma unroll
    for (int i = 0; i < 10; ++i) {
      float gz = 0.f;
      #pragma unroll
      for (int j = 0; j < 10; ++j) gz += Gh[w * 100 + i * 10 + j] * zv[w * 10 + j];
      s += zv[w * 10 + i] * gz;
    }
    sv[w] = s;
  }
  float mx = fmaxf(fmaxf(fmaxf(sv[0], sv[1]), fmaxf(sv[2], sv[3])), sv[4]);
  float sum = 0.f;
  #pragma unroll
  for (int w = 0; w < 5; ++w) sum += expf(sv[w] - mx);
  float lse = mx + logf(sum);
  float* o = out + (size_t)q * 5;
  #pragma unroll
  for (int w = 0; w < 5; ++w) o[w] = sv[w] - lse;
}

extern "C" void kernel_launch(void* const* d_in, const int* in_sizes, int n_in,
                              void* d_out, int out_size, void* d_ws, size_t ws_size,
                              hipStream_t stream) {
  const float* support = (const float*)d_in[0];
  const int*   labels  = (const int*)d_in[1];
  const float* query   = (const float*)d_in[2];
  float* out = (float*)d_out;
  char* ws = (char*)d_ws;

  double*         G    = (double*)(ws + WS_G_OFF);
  float*          Ghat = (float*)(ws + WS_GH_OFF);
  unsigned short* P    = (unsigned short*)(ws + WS_P_OFF);
  float*          Z    = (float*)(ws + WS_Z_OFF);

  int nq = in_sizes[2] / 1024;          // 16384
  int zs_blocks = nq / 16 + 5;          // 1024 GEMM blocks + 5 solve
  int post_blocks = nq / 256;           // 64

  hipLaunchKernelGGL(dsn_prep, dim3(149), dim3(256), 0, stream, support, labels, G, P);
  hipLaunchKernelGGL(dsn_zs,   dim3(zs_blocks), dim3(256), 0, stream,
                     query, P, G, Ghat, Z);
  hipLaunchKernelGGL(dsn_post, dim3(post_blocks), dim3(256), 0, stream, Ghat, Z, out);
}